// Round 1
// baseline (151.002 us; speedup 1.0000x reference)
//
#include <hip/hip_runtime.h>

// AdaptedEntropyModel: sym = searchsorted(mids, inputs-means), deq = uv[sym]+means,
// cdf = quantized per-channel CDF (192 x 66).
// Outputs written as float32 (harness reads concatenated outputs as float).

#define LVALS 60
#define NMIDS 59
#define MIDS_PAD 64
#define MLEN 64

__global__ __launch_bounds__(256) void sym_deq_kernel(
    const float* __restrict__ inputs,
    const float* __restrict__ means,
    const float* __restrict__ uv,
    float* __restrict__ out_sym,
    float* __restrict__ out_deq,
    int n4)
{
    __shared__ float uv_s[LVALS];
    __shared__ float mids_s[MIDS_PAD];

    const int t = threadIdx.x;
    if (t < LVALS) uv_s[t] = uv[t];
    if (t >= LVALS && t < MIDS_PAD + LVALS) mids_s[t - LVALS + NMIDS - (MIDS_PAD - NMIDS) > NMIDS ? 0 : 0] = 0.0f; // placeholder no-op
    __syncthreads();
    if (t < MIDS_PAD) {
        // mids[i] = 0.5*(uv[i+1]+uv[i]) for i<59; pad with +INF
        mids_s[t] = (t < NMIDS) ? 0.5f * (uv_s[t + 1] + uv_s[t]) : __int_as_float(0x7f800000);
    }
    __syncthreads();

    const float4* __restrict__ in4 = (const float4*)inputs;
    const float4* __restrict__ mn4 = (const float4*)means;
    float4* __restrict__ sym4 = (float4*)out_sym;
    float4* __restrict__ deq4 = (float4*)out_deq;

    const int stride = gridDim.x * blockDim.x;
    for (int i = blockIdx.x * blockDim.x + t; i < n4; i += stride) {
        float4 a = in4[i];
        float4 m = mn4[i];
        float4 s, d;
        float* ap = &a.x;
        float* mp = &m.x;
        float* sp = &s.x;
        float* dp = &d.x;
#pragma unroll
        for (int k = 0; k < 4; ++k) {
            const float v = ap[k] - mp[k];
            // branchless lower_bound over 64 (padded) sorted elems: count of mids < v
            int c = 0;
            c += (mids_s[c + 31] < v) ? 32 : 0;
            c += (mids_s[c + 15] < v) ? 16 : 0;
            c += (mids_s[c + 7]  < v) ? 8  : 0;
            c += (mids_s[c + 3]  < v) ? 4  : 0;
            c += (mids_s[c + 1]  < v) ? 2  : 0;
            c += (mids_s[c]      < v) ? 1  : 0;
            sp[k] = (float)c;
            dp[k] = uv_s[c] + mp[k];
        }
        sym4[i] = s;
        deq4[i] = d;
    }
}

__global__ __launch_bounds__(64) void cdf_kernel(
    const float* __restrict__ pmf,
    const float* __restrict__ tail_mass,
    const int* __restrict__ pmf_length,
    float* __restrict__ out_cdf,
    int C)
{
    const int c = blockIdx.x * blockDim.x + threadIdx.x;
    if (c >= C) return;

    const int plen = pmf_length[c];        // in [8, 64]
    const float tail = tail_mass[c];
    const float* p = pmf + c * MLEN;

    // pass 1: total
    float run = 0.0f;
    for (int i = 0; i <= MLEN; ++i) {
        float v = (i < MLEN) ? p[i] : 0.0f;
        v = (i < plen) ? v : 0.0f;
        if (i == plen) v += tail;
        run += v;
    }
    const float total = run;

    float* o = out_cdf + c * (MLEN + 2);
    o[0] = 0.0f;

    // pass 2: emit cdf body; zero beyond plen+1 (d_out is poisoned each call)
    run = 0.0f;
    for (int i = 0; i <= MLEN; ++i) {
        float v = (i < MLEN) ? p[i] : 0.0f;
        v = (i < plen) ? v : 0.0f;
        if (i == plen) v += tail;
        run += v;
        const float val = rintf(run / total * 65536.0f);
        o[i + 1] = (i <= plen) ? val : 0.0f;
    }
}

extern "C" void kernel_launch(void* const* d_in, const int* in_sizes, int n_in,
                              void* d_out, int out_size, void* d_ws, size_t ws_size,
                              hipStream_t stream) {
    const float* inputs     = (const float*)d_in[0];
    const float* means      = (const float*)d_in[1];
    const float* uv         = (const float*)d_in[2];
    const float* pmf        = (const float*)d_in[3];
    const float* tail_mass  = (const float*)d_in[4];
    const int*   pmf_length = (const int*)d_in[5];

    const int N = in_sizes[0];          // 16*192*48*64 = 9437184
    const int C = in_sizes[5];          // 192

    float* out = (float*)d_out;
    float* out_sym = out;
    float* out_deq = out + N;
    float* out_cdf = out + 2 * (size_t)N;

    const int n4 = N / 4;               // N divisible by 4
    const int block = 256;
    int grid = (n4 + block - 1) / block;
    if (grid > 2048) grid = 2048;

    sym_deq_kernel<<<grid, block, 0, stream>>>(inputs, means, uv, out_sym, out_deq, n4);
    cdf_kernel<<<(C + 63) / 64, 64, 0, stream>>>(pmf, tail_mass, pmf_length, out_cdf, C);
}

// Round 2
// 145.900 us; speedup vs baseline: 1.0350x; 1.0350x over previous
//
#include <hip/hip_runtime.h>

// AdaptedEntropyModel: sym = searchsorted(mids, inputs-means), deq = uv[sym]+means,
// cdf = quantized per-channel CDF (192 x 66). All outputs written as float32.
//
// Fused single launch: block 0 computes the (tiny) per-channel CDF; blocks 1..G
// run the streaming sym/deq pass with float4 non-temporal loads/stores.

#define LVALS 60
#define NMIDS 59
#define MIDS_PAD 64
#define MLEN 64

typedef float f32x4 __attribute__((ext_vector_type(4)));

__global__ __launch_bounds__(256) void entropy_fused_kernel(
    const float* __restrict__ inputs,
    const float* __restrict__ means,
    const float* __restrict__ uv,
    const float* __restrict__ pmf,
    const float* __restrict__ tail_mass,
    const int* __restrict__ pmf_length,
    float* __restrict__ out_sym,
    float* __restrict__ out_deq,
    float* __restrict__ out_cdf,
    int n4, int C)
{
    if (blockIdx.x == 0) {
        // ---- CDF path: one thread per channel (192 active of 256) ----
        const int c = threadIdx.x;
        if (c >= C) return;

        const int plen = pmf_length[c];        // in [8, 64]
        const float tail = tail_mass[c];
        const float* p = pmf + c * MLEN;

        // pass 1: total mass
        float run = 0.0f;
        for (int i = 0; i <= MLEN; ++i) {
            float v = (i < MLEN) ? p[i] : 0.0f;
            v = (i < plen) ? v : 0.0f;
            if (i == plen) v += tail;
            run += v;
        }
        const float total = run;

        float* o = out_cdf + c * (MLEN + 2);
        o[0] = 0.0f;

        // pass 2: emit quantized cdf body; zero past plen+1 (d_out is poisoned)
        run = 0.0f;
        for (int i = 0; i <= MLEN; ++i) {
            float v = (i < MLEN) ? p[i] : 0.0f;
            v = (i < plen) ? v : 0.0f;
            if (i == plen) v += tail;
            run += v;
            const float val = rintf(run / total * 65536.0f);
            o[i + 1] = (i <= plen) ? val : 0.0f;
        }
        return;
    }

    // ---- sym/deq path: streaming, memory-bound ----
    __shared__ float uv_s[LVALS];
    __shared__ float mids_s[MIDS_PAD];

    const int t = threadIdx.x;
    if (t < LVALS) uv_s[t] = uv[t];
    __syncthreads();
    if (t < MIDS_PAD) {
        // mids[i] = 0.5*(uv[i+1]+uv[i]) for i<59; pad with +INF so the
        // 6-step branchless lower_bound runs over a 64-entry table.
        mids_s[t] = (t < NMIDS) ? 0.5f * (uv_s[t + 1] + uv_s[t])
                                : __int_as_float(0x7f800000);
    }
    __syncthreads();

    const f32x4* __restrict__ in4 = (const f32x4*)inputs;
    const f32x4* __restrict__ mn4 = (const f32x4*)means;
    f32x4* __restrict__ sym4 = (f32x4*)out_sym;
    f32x4* __restrict__ deq4 = (f32x4*)out_deq;

    const int stride = (gridDim.x - 1) * blockDim.x;
    for (int i = (blockIdx.x - 1) * blockDim.x + t; i < n4; i += stride) {
        f32x4 a = __builtin_nontemporal_load(in4 + i);
        f32x4 m = __builtin_nontemporal_load(mn4 + i);
        f32x4 s, d;
#pragma unroll
        for (int k = 0; k < 4; ++k) {
            const float v = a[k] - m[k];
            // branchless lower_bound: count of mids < v  (== searchsorted 'left')
            int c = 0;
            c += (mids_s[c + 31] < v) ? 32 : 0;
            c += (mids_s[c + 15] < v) ? 16 : 0;
            c += (mids_s[c + 7]  < v) ? 8  : 0;
            c += (mids_s[c + 3]  < v) ? 4  : 0;
            c += (mids_s[c + 1]  < v) ? 2  : 0;
            c += (mids_s[c]      < v) ? 1  : 0;
            s[k] = (float)c;
            d[k] = uv_s[c] + m[k];
        }
        __builtin_nontemporal_store(s, sym4 + i);
        __builtin_nontemporal_store(d, deq4 + i);
    }
}

extern "C" void kernel_launch(void* const* d_in, const int* in_sizes, int n_in,
                              void* d_out, int out_size, void* d_ws, size_t ws_size,
                              hipStream_t stream) {
    const float* inputs     = (const float*)d_in[0];
    const float* means      = (const float*)d_in[1];
    const float* uv         = (const float*)d_in[2];
    const float* pmf        = (const float*)d_in[3];
    const float* tail_mass  = (const float*)d_in[4];
    const int*   pmf_length = (const int*)d_in[5];

    const int N = in_sizes[0];          // 16*192*48*64 = 9437184
    const int C = in_sizes[5];          // 192

    float* out = (float*)d_out;
    float* out_sym = out;
    float* out_deq = out + N;
    float* out_cdf = out + 2 * (size_t)N;

    const int n4 = N / 4;               // N divisible by 4
    const int block = 256;
    int grid_sym = (n4 + block - 1) / block;
    if (grid_sym > 2048) grid_sym = 2048;   // 8 wg/CU, grid-stride the rest

    entropy_fused_kernel<<<grid_sym + 1, block, 0, stream>>>(
        inputs, means, uv, pmf, tail_mass, pmf_length,
        out_sym, out_deq, out_cdf, n4, C);
}

// Round 3
// 144.464 us; speedup vs baseline: 1.0453x; 1.0099x over previous
//
#include <hip/hip_runtime.h>

// AdaptedEntropyModel: sym = searchsorted(mids, inputs-means), deq = uv[sym]+means,
// cdf = quantized per-channel CDF (192 x 66). All outputs written as float32.
//
// Single fused launch, exact-cover single-pass: blocks 1..4608 each process
// exactly 8 elements/thread (2x float4 in, 2x2 float4 out, non-temporal).
// Block 0 computes the tiny per-channel CDF.

#define LVALS 60
#define NMIDS 59
#define MIDS_PAD 64
#define MLEN 64

typedef float f32x4 __attribute__((ext_vector_type(4)));

__global__ __launch_bounds__(256) void entropy_fused_kernel(
    const float* __restrict__ inputs,
    const float* __restrict__ means,
    const float* __restrict__ uv,
    const float* __restrict__ pmf,
    const float* __restrict__ tail_mass,
    const int* __restrict__ pmf_length,
    float* __restrict__ out_sym,
    float* __restrict__ out_deq,
    float* __restrict__ out_cdf,
    int n8, int C)
{
    if (blockIdx.x == 0) {
        // ---- CDF path: one thread per channel (192 active of 256) ----
        const int c = threadIdx.x;
        if (c >= C) return;

        const int plen = pmf_length[c];        // in [8, 64]
        const float tail = tail_mass[c];
        const float* p = pmf + c * MLEN;

        // pass 1: total mass
        float run = 0.0f;
        for (int i = 0; i <= MLEN; ++i) {
            float v = (i < MLEN) ? p[i] : 0.0f;
            v = (i < plen) ? v : 0.0f;
            if (i == plen) v += tail;
            run += v;
        }
        const float total = run;

        float* o = out_cdf + c * (MLEN + 2);
        o[0] = 0.0f;

        // pass 2: emit quantized cdf body; zero past plen+1 (d_out is poisoned)
        run = 0.0f;
        for (int i = 0; i <= MLEN; ++i) {
            float v = (i < MLEN) ? p[i] : 0.0f;
            v = (i < plen) ? v : 0.0f;
            if (i == plen) v += tail;
            run += v;
            const float val = rintf(run / total * 65536.0f);
            o[i + 1] = (i <= plen) ? val : 0.0f;
        }
        return;
    }

    // ---- sym/deq path: streaming, memory-bound, exact cover ----
    __shared__ float uv_s[LVALS];
    __shared__ float mids_s[MIDS_PAD];

    const int t = threadIdx.x;
    if (t < LVALS) uv_s[t] = uv[t];
    __syncthreads();
    if (t < MIDS_PAD) {
        // mids[i] = 0.5*(uv[i+1]+uv[i]) for i<59; pad with +INF so the
        // 6-step branchless lower_bound runs over a 64-entry table.
        mids_s[t] = (t < NMIDS) ? 0.5f * (uv_s[t + 1] + uv_s[t])
                                : __int_as_float(0x7f800000);
    }
    __syncthreads();

    const int i = (blockIdx.x - 1) * blockDim.x + t;   // i in [0, n8)
    if (i >= n8) return;                                // never taken at bench shape

    const f32x4* __restrict__ in4 = (const f32x4*)inputs;
    const f32x4* __restrict__ mn4 = (const f32x4*)means;
    f32x4* __restrict__ sym4 = (f32x4*)out_sym;
    f32x4* __restrict__ deq4 = (f32x4*)out_deq;

    const int j = 2 * i;
    // issue all 4 independent 16B loads up front (MLP)
    f32x4 a0 = __builtin_nontemporal_load(in4 + j);
    f32x4 a1 = __builtin_nontemporal_load(in4 + j + 1);
    f32x4 m0 = __builtin_nontemporal_load(mn4 + j);
    f32x4 m1 = __builtin_nontemporal_load(mn4 + j + 1);

    f32x4 s0, s1, d0, d1;
#pragma unroll
    for (int k = 0; k < 4; ++k) {
        {
            const float v = a0[k] - m0[k];
            int c = 0;
            c += (mids_s[c + 31] < v) ? 32 : 0;
            c += (mids_s[c + 15] < v) ? 16 : 0;
            c += (mids_s[c + 7]  < v) ? 8  : 0;
            c += (mids_s[c + 3]  < v) ? 4  : 0;
            c += (mids_s[c + 1]  < v) ? 2  : 0;
            c += (mids_s[c]      < v) ? 1  : 0;
            s0[k] = (float)c;
            d0[k] = uv_s[c] + m0[k];
        }
        {
            const float v = a1[k] - m1[k];
            int c = 0;
            c += (mids_s[c + 31] < v) ? 32 : 0;
            c += (mids_s[c + 15] < v) ? 16 : 0;
            c += (mids_s[c + 7]  < v) ? 8  : 0;
            c += (mids_s[c + 3]  < v) ? 4  : 0;
            c += (mids_s[c + 1]  < v) ? 2  : 0;
            c += (mids_s[c]      < v) ? 1  : 0;
            s1[k] = (float)c;
            d1[k] = uv_s[c] + m1[k];
        }
    }
    __builtin_nontemporal_store(s0, sym4 + j);
    __builtin_nontemporal_store(s1, sym4 + j + 1);
    __builtin_nontemporal_store(d0, deq4 + j);
    __builtin_nontemporal_store(d1, deq4 + j + 1);
}

extern "C" void kernel_launch(void* const* d_in, const int* in_sizes, int n_in,
                              void* d_out, int out_size, void* d_ws, size_t ws_size,
                              hipStream_t stream) {
    const float* inputs     = (const float*)d_in[0];
    const float* means      = (const float*)d_in[1];
    const float* uv         = (const float*)d_in[2];
    const float* pmf        = (const float*)d_in[3];
    const float* tail_mass  = (const float*)d_in[4];
    const int*   pmf_length = (const int*)d_in[5];

    const int N = in_sizes[0];          // 16*192*48*64 = 9437184
    const int C = in_sizes[5];          // 192

    float* out = (float*)d_out;
    float* out_sym = out;
    float* out_deq = out + N;
    float* out_cdf = out + 2 * (size_t)N;

    const int n8 = N / 8;               // 1179648 = 4608 * 256 (exact cover)
    const int block = 256;
    const int grid_sym = (n8 + block - 1) / block;   // 4608

    entropy_fused_kernel<<<grid_sym + 1, block, 0, stream>>>(
        inputs, means, uv, pmf, tail_mass, pmf_length,
        out_sym, out_deq, out_cdf, n8, C);
}